// Round 7
// baseline (68.802 us; speedup 1.0000x reference)
//
#include <hip/hip_runtime.h>

#define B_ROWS 8192
#define IN_DIM 512
#define OUT_DIM 512
#define NDEG 8                 // DEGREE+1
#define KDIM (IN_DIM * NDEG)   // 4096
#define ZSLICES 4
#define NKT 16                 // K-tiles (of 64) per z-slice

typedef short bf16x8 __attribute__((ext_vector_type(8)));
typedef float f32x4  __attribute__((ext_vector_type(4)));

__device__ __forceinline__ unsigned short f2bf(float f) {
  unsigned u = __float_as_uint(f);
  u += 0x7fffu + ((u >> 16) & 1u);   // RNE
  return (unsigned short)(u >> 16);
}

__device__ __forceinline__ void laguerre8(float t, float* L) {
  L[0] = 1.0f;
  L[1] = 1.5f - t;
#pragma unroll
  for (int k = 2; k < NDEG; ++k)
    L[k] = ((2.0f * (float)k - 0.5f - t) * L[k - 1] -
            ((float)k - 0.5f) * L[k - 2]) * (1.0f / (float)k);
}

// fast tanh: (e^{2x}-1)/(e^{2x}+1); safe for |x| < 40 (x ~ N(0,1))
__device__ __forceinline__ float ftanh(float x) {
  float e2 = __expf(2.0f * x);
  return (e2 - 1.0f) * (1.0f / (e2 + 1.0f));
}

__device__ __forceinline__ uint4 bpack(float xv) {
  float L[NDEG];
  laguerre8(ftanh(xv), L);
  uint4 v;
  v.x = (unsigned)f2bf(L[0]) | ((unsigned)f2bf(L[1]) << 16);
  v.y = (unsigned)f2bf(L[2]) | ((unsigned)f2bf(L[3]) << 16);
  v.z = (unsigned)f2bf(L[4]) | ((unsigned)f2bf(L[5]) << 16);
  v.w = (unsigned)f2bf(L[6]) | ((unsigned)f2bf(L[7]) << 16);
  return v;
}

// ---- pass 1: coeffs -> Bt bricks (pre-swizzled; same layout as rounds 5/6) ------
// chunk = (rowblk*64 + ktile)*1024 + (rb>>6)*512 + (rb&63)*8 + (c ^ (rb&7))
__global__ void prep_kernel(const float* __restrict__ cf, unsigned short* __restrict__ Bt) {
  int idx = blockIdx.x * 256 + threadIdx.x;   // i*512 + o
  int i = idx >> 9, o = idx & 511;
  const float4* cp = (const float4*)(cf + (size_t)idx * 8);
  float4 c0 = cp[0], c1 = cp[1];
  uint4 v;
  v.x = (unsigned)f2bf(c0.x) | ((unsigned)f2bf(c0.y) << 16);
  v.y = (unsigned)f2bf(c0.z) | ((unsigned)f2bf(c0.w) << 16);
  v.z = (unsigned)f2bf(c1.x) | ((unsigned)f2bf(c1.y) << 16);
  v.w = (unsigned)f2bf(c1.z) | ((unsigned)f2bf(c1.w) << 16);
  int h = o >> 7, rb = o & 127, t = i >> 3, c = i & 7;
  size_t chunk = ((size_t)(h * 64 + t)) * 1024 + (rb >> 6) * 512 + (rb & 63) * 8 + (c ^ (rb & 7));
  ((uint4*)Bt)[chunk] = v;
}

// ---- pass 2: fused basis + GEMM, 8-phase schedule -------------------------------
// 8 waves (2m x 4n), 256x256 tile, wave-tile 128x64. LDS 144 KB:
//   A ring 2x32KB (computed in-kernel, ds_write swizzled brick image)
//   B ring 2x32KB (gl_lds from pre-swizzled Bt bricks)
//   x ring 2x8KB f32 (gl_lds width-4; wave reads only rows it staged)

#define VM(N) { asm volatile("s_waitcnt vmcnt(" #N ")" ::: "memory");  \
                __builtin_amdgcn_sched_barrier(0); }

#define XSTAGE(tt, nb, h)                                                           \
  {                                                                                 \
    const float* xs = x + (size_t)(My * 256 + (h) * 128 + w * 16 + (lane >> 3)) * 512 \
                        + (z * 16 + (tt)) * 8 + (lane & 7);                         \
    unsigned short* xd = lds + 65536 + (nb) * 4096 + (h) * 2048 + w * 256;          \
    __builtin_amdgcn_global_load_lds(                                               \
        (const __attribute__((address_space(1))) unsigned int*)xs,                  \
        (__attribute__((address_space(3))) unsigned int*)xd, 4, 0, 0);              \
    __builtin_amdgcn_global_load_lds(                                               \
        (const __attribute__((address_space(1))) unsigned int*)(xs + 8 * 512),      \
        (__attribute__((address_space(3))) unsigned int*)(xd + 128), 4, 0, 0);      \
  }

#define BSTAGE(tt, nb, h)                                                           \
  {                                                                                 \
    const size_t c0_ = ((size_t)((n * 2 + (h)) * 64 + z * 16 + (tt))) * 1024        \
                       + w * 64 + lane;                                             \
    unsigned short* d_ = lds + 32768 + (nb) * 16384 + (h) * 8192 + w * 512;         \
    __builtin_amdgcn_global_load_lds(                                               \
        (const __attribute__((address_space(1))) unsigned int*)(Bg + c0_),          \
        (__attribute__((address_space(3))) unsigned int*)d_, 16, 0, 0);             \
    __builtin_amdgcn_global_load_lds(                                               \
        (const __attribute__((address_space(1))) unsigned int*)(Bg + c0_ + 512),    \
        (__attribute__((address_space(3))) unsigned int*)(d_ + 4096), 16, 0, 0);    \
  }

// compute one A half (128 rows x 64 k) for next tile: 2 evals/thread.
// Reads x rows this wave staged (rb in [w*16, w*16+16)) -> per-wave vmcnt gates ok.
#define AC_HALF(nb, h)                                                              \
  {                                                                                 \
    float2 xv = *(const float2*)((const char*)lds + 131072 + (nb) * 8192            \
                                 + (h) * 4096 + xoff);                              \
    uint4 v0 = bpack(xv.x), v1 = bpack(xv.y);                                       \
    unsigned short* dA = lds + (nb) * 16384 + (h) * 8192 + chkbase * 8;             \
    *(uint4*)(dA + c0s * 8) = v0;                                                   \
    *(uint4*)(dA + c1s * 8) = v1;                                                   \
  }

#define PHASE(AB, BB, MQ, KS, LOADBF, STAGE, POST)                                  \
  {                                                                                 \
    const unsigned short* Ab_ = lds + (AB) * 16384 + wm * 8192 + (MQ) * 4096        \
                                + arow * 64;                                        \
    _Pragma("unroll") for (int m4 = 0; m4 < 4; ++m4)                                \
      af[m4] = *(const bf16x8*)(Ab_ + m4 * 1024 + (e ^ ((KS) * 32)));               \
    if (LOADBF) {                                                                   \
      const unsigned short* Bb_ = lds + 32768 + (BB) * 16384 + (wn >> 1) * 8192     \
                                  + (wn & 1) * 4096 + arow * 64;                    \
      _Pragma("unroll") for (int ni = 0; ni < 4; ++ni)                              \
        bfr[ni] = *(const bf16x8*)(Bb_ + ni * 1024 + (e ^ ((KS) * 32)));            \
    }                                                                               \
    STAGE;                                                                          \
    __builtin_amdgcn_s_barrier();                                                   \
    asm volatile("s_waitcnt lgkmcnt(0)" ::: "memory");                              \
    __builtin_amdgcn_sched_barrier(0);                                              \
    __builtin_amdgcn_s_setprio(1);                                                  \
    _Pragma("unroll") for (int m4 = 0; m4 < 4; ++m4)                                \
      _Pragma("unroll") for (int ni = 0; ni < 4; ++ni)                              \
        acc[(MQ) * 4 + m4][ni] = __builtin_amdgcn_mfma_f32_16x16x32_bf16(           \
            af[m4], bfr[ni], acc[(MQ) * 4 + m4][ni], 0, 0, 0);                      \
    __builtin_amdgcn_s_setprio(0);                                                  \
    POST;                                                                           \
    __builtin_amdgcn_s_barrier();                                                   \
  }

__global__ __launch_bounds__(512, 2) void gemm_kernel(const float* __restrict__ x,
                                                      const unsigned short* __restrict__ Bt,
                                                      unsigned short* __restrict__ P) {
  __shared__ __align__(16) unsigned short lds[73728];   // 144 KB

  const int tid = threadIdx.x;
  const int lane = tid & 63;
  const int w = tid >> 6;
  const int wm = w >> 2, wn = w & 3;

  // bijective decode, x/A-panel sharers (same My, all n,z) co-XCD
  const int g = blockIdx.x;               // 0..255
  const int j0 = g >> 3, xx = g & 7;
  const int My = ((j0 >> 3) << 3) | xx;   // 0..31
  const int n = (j0 >> 2) & 1;            // 0..1
  const int z = j0 & 3;                   // 0..3

  const uint4* Bg = (const uint4*)Bt;

  const int arow = lane & 15, hi = lane >> 4;
  const int e = (hi ^ (arow & 7)) * 8;    // swizzled chunk offset (shorts)

  // A-compute per-thread constants: 2 evals (row rb, i-chunks ii0, ii0+1)
  const int rb = tid >> 2, ii0 = (tid & 3) * 2, sw = rb & 7;
  const int chkbase = (rb >> 6) * 512 + (rb & 63) * 8;
  const int c0s = ii0 ^ sw, c1s = (ii0 + 1) ^ sw;
  const int xoff = (rb * 8 + ii0) * 4;    // bytes within x half

  f32x4 zero = {0.f, 0.f, 0.f, 0.f};
  f32x4 acc[8][4];
#pragma unroll
  for (int mi = 0; mi < 8; ++mi)
#pragma unroll
    for (int ni = 0; ni < 4; ++ni) acc[mi][ni] = zero;

  bf16x8 af[4], bfr[4];

  // ---- prologue: stage x(0),B(0); compute A(0) ----
  XSTAGE(0, 0, 0); XSTAGE(0, 0, 1);
  BSTAGE(0, 0, 0); BSTAGE(0, 0, 1);
  VM(4);                                   // x(0) landed; B(0) in flight
  AC_HALF(0, 0); AC_HALF(0, 1);
  asm volatile("s_waitcnt lgkmcnt(0)" ::: "memory");
  VM(0);                                   // B(0) landed
  __builtin_amdgcn_s_barrier();

  // ---- main loop: tile t in buf t&1; stage x/B/A for t+1 into buf (t+1)&1 ----
#pragma unroll 1
  for (int t = 0; t < NKT - 1; ++t) {
    const int ct = t & 1, nb = ct ^ 1;
    const int tt = t + 1;
    PHASE(ct, ct, 0, 0, 1, { XSTAGE(tt, nb, 0); BSTAGE(tt, nb, 0); }, {});
    PHASE(ct, ct, 1, 0, 0, { XSTAGE(tt, nb, 1); BSTAGE(tt, nb, 1); }, {});
    PHASE(ct, ct, 0, 1, 1, {}, { VM(6); AC_HALF(nb, 0); });
    PHASE(ct, ct, 1, 1, 0, {},
          { VM(2); AC_HALF(nb, 1);
            asm volatile("s_waitcnt lgkmcnt(0)" ::: "memory");   // publish A(t+1)
            VM(0); });                                           // B(t+1) landed
  }
  // ---- tail: tile 15 (buf 1), no staging ----
  PHASE(1, 1, 0, 0, 1, {}, {});
  PHASE(1, 1, 1, 0, 0, {}, {});
  PHASE(1, 1, 0, 1, 1, {}, {});
  PHASE(1, 1, 1, 1, 0, {}, {});

  // ---- epilogue: bf16 via per-wave LDS bounce (swizzled) -> uint4 line stores ----
  unsigned short* W = lds + w * 8192;    // 128 rows x 64 shorts per wave
#pragma unroll
  for (int mi = 0; mi < 8; ++mi)
#pragma unroll
    for (int ni = 0; ni < 4; ++ni) {
      int col = ni * 16 + arow;
      int c8 = col >> 3, cpos = col & 7;
#pragma unroll
      for (int r = 0; r < 4; ++r) {
        int row = mi * 16 + hi * 4 + r;
        W[row * 64 + ((c8 ^ (row & 7)) << 3) + cpos] = f2bf(acc[mi][ni][r]);
      }
    }
  const int rr = lane >> 3, cc = lane & 7;
#pragma unroll
  for (int it = 0; it < 16; ++it) {
    int row = it * 8 + rr;
    uint4 v = *(uint4*)&W[row * 64 + ((cc ^ (row & 7)) << 3)];
    size_t pr = ((size_t)z * B_ROWS + My * 256 + wm * 128 + row) * 512 + n * 256 + wn * 64 + cc * 8;
    *(uint4*)&P[pr] = v;
  }
}

// ---- pass 3: out = sum of bf16 partials, f32 ------------------------------------
__global__ void reduce_kernel(const unsigned short* __restrict__ P, float* __restrict__ out) {
  size_t t = (size_t)blockIdx.x * 256 + threadIdx.x;
  const uint4* p = (const uint4*)P;
  const size_t stride = (size_t)B_ROWS * OUT_DIM / 8;
  float s[8] = {0, 0, 0, 0, 0, 0, 0, 0};
#pragma unroll
  for (int zz = 0; zz < ZSLICES; ++zz) {
    uint4 v = p[t + zz * stride];
    unsigned q[4] = {v.x, v.y, v.z, v.w};
#pragma unroll
    for (int j = 0; j < 4; ++j) {
      s[2 * j]     += __uint_as_float((q[j] & 0xffffu) << 16);
      s[2 * j + 1] += __uint_as_float(q[j] & 0xffff0000u);
    }
  }
  float4 o0 = {s[0], s[1], s[2], s[3]}, o1 = {s[4], s[5], s[6], s[7]};
  ((float4*)out)[t * 2]     = o0;
  ((float4*)out)[t * 2 + 1] = o1;
}

// ---- fallback -------------------------------------------------------------------
__global__ void naive_kernel(const float* __restrict__ x, const float* __restrict__ c,
                             float* __restrict__ out) {
  __shared__ float bas[IN_DIM * NDEG];
  int b = blockIdx.x;
  for (int i = threadIdx.x; i < IN_DIM; i += 256) {
    float t = tanhf(x[(size_t)b * IN_DIM + i]);
    float L[NDEG];
    laguerre8(t, L);
#pragma unroll
    for (int d = 0; d < NDEG; ++d) bas[i * NDEG + d] = L[d];
  }
  __syncthreads();
  for (int o = threadIdx.x; o < OUT_DIM; o += 256) {
    float acc = 0.f;
    for (int i = 0; i < IN_DIM; ++i) {
      const float* cp = c + ((size_t)i * OUT_DIM + o) * NDEG;
#pragma unroll
      for (int d = 0; d < NDEG; ++d) acc += bas[i * NDEG + d] * cp[d];
    }
    out[(size_t)b * OUT_DIM + o] = acc;
  }
}

extern "C" void kernel_launch(void* const* d_in, const int* in_sizes, int n_in,
                              void* d_out, int out_size, void* d_ws, size_t ws_size,
                              hipStream_t stream) {
  const float* x    = (const float*)d_in[0];
  const float* coef = (const float*)d_in[1];
  float* out = (float*)d_out;

  const size_t P_BYTES  = (size_t)ZSLICES * B_ROWS * OUT_DIM * 2; // 32 MiB
  const size_t BT_BYTES = (size_t)OUT_DIM * KDIM * 2;             // 4 MiB

  if (ws_size >= P_BYTES + BT_BYTES) {   // 36 MiB (ws proven >= 100 MiB earlier)
    unsigned short* Pp = (unsigned short*)d_ws;
    unsigned short* Bt = (unsigned short*)((char*)d_ws + P_BYTES);
    prep_kernel<<<(IN_DIM * OUT_DIM) / 256, 256, 0, stream>>>(coef, Bt);
    gemm_kernel<<<256, 512, 0, stream>>>(x, Bt, Pp);
    reduce_kernel<<<(B_ROWS * OUT_DIM / 8) / 256, 256, 0, stream>>>(Pp, out);
  } else {
    naive_kernel<<<B_ROWS, 256, 0, stream>>>(x, coef, out);
  }
}